// Round 1
// baseline (266.582 us; speedup 1.0000x reference)
//
#include <hip/hip_runtime.h>
#include <hip/hip_bf16.h>

typedef unsigned short u16;
typedef unsigned int u32;
typedef __attribute__((ext_vector_type(8))) short bf16x8;
typedef __attribute__((ext_vector_type(4))) float f32x4;

// ---------- helpers ----------
__device__ __forceinline__ u16 f2bf(float f) {
    u32 u = __float_as_uint(f);
    u32 r = (u + 0x7fffu + ((u >> 16) & 1u)) >> 16;   // RNE
    return (u16)r;
}
__device__ __forceinline__ float sx(float v, int m) { return __shfl_xor(v, m, 64); }

// sizes
#define MROWS 32768          // 8*4096
#define IN_D  512
#define OUT_D 512
#define KP    544            // 512 + 32 (zq pad)
#define NQ    6

// ws layout (bytes)
#define WS_XBF   0                       // u16 [32768][544]  = 35,651,584 B
#define WS_WBF   35651584                // u16 [512][544]    = 557,056 B
#define WS_WTRIG (35651584 + 557056)     // float [72]

// ---------------------------------------------------------------------------
// kernel 0: pack W' = [skip_w | exit_w | 0] -> bf16 [512][544]; wtrig
// ---------------------------------------------------------------------------
__global__ void k_setup(const float* __restrict__ skip_w,
                        const float* __restrict__ exit_w,
                        const float* __restrict__ vqc_w,
                        u16* __restrict__ Wbf,
                        float* __restrict__ wtrig) {
    int n = blockIdx.x;           // 512 blocks
    int t = threadIdx.x;          // 64 threads
    for (int c = t; c < KP; c += 64) {
        float v;
        if (c < 512)      v = skip_w[n * 512 + c];
        else if (c < 518) v = exit_w[n * 6 + (c - 512)];
        else              v = 0.0f;
        Wbf[n * KP + c] = f2bf(v);
    }
    if (blockIdx.x == 0 && t < 36) {
        float w = vqc_w[t];                    // [2][3][6] row-major
        wtrig[2 * t]     = cosf(0.5f * w);
        wtrig[2 * t + 1] = sinf(0.5f * w);
    }
}

// ---------------------------------------------------------------------------
// kernel 1: per-row entry-dot + 6-qubit statevector sim (wave = statevector)
// writes A' = [x (bf16) | z+q (bf16, 6) | zeros] as [32768][544]
// ---------------------------------------------------------------------------
__global__ __launch_bounds__(256) void k_zq(const float* __restrict__ x,
                                            const float* __restrict__ entry_w,
                                            const float* __restrict__ entry_b,
                                            const float* __restrict__ wtrig,
                                            u16* __restrict__ xbf) {
    const int lane = threadIdx.x & 63;
    const int row  = blockIdx.x * 4 + (threadIdx.x >> 6);

    // ---- load x row slice (8 floats/lane) ----
    const float4* xp = (const float4*)(x + (size_t)row * IN_D) + lane * 2;
    float4 xa = xp[0], xb = xp[1];

    // ---- write bf16 copy of x into A' ----
    union { u16 u[8]; uint4 v; } pk;
    pk.u[0] = f2bf(xa.x); pk.u[1] = f2bf(xa.y); pk.u[2] = f2bf(xa.z); pk.u[3] = f2bf(xa.w);
    pk.u[4] = f2bf(xb.x); pk.u[5] = f2bf(xb.y); pk.u[6] = f2bf(xb.z); pk.u[7] = f2bf(xb.w);
    *(uint4*)(xbf + (size_t)row * KP + lane * 8) = pk.v;

    // ---- z = entry_w @ x_row + entry_b (6 butterfly reductions) ----
    float z[NQ];
#pragma unroll
    for (int j = 0; j < NQ; ++j) {
        const float4* wp = (const float4*)(entry_w + j * IN_D) + lane * 2;
        float4 wa = wp[0], wb = wp[1];
        float d = xa.x * wa.x + xa.y * wa.y + xa.z * wa.z + xa.w * wa.w
                + xb.x * wb.x + xb.y * wb.y + xb.z * wb.z + xb.w * wb.w;
#pragma unroll
        for (int off = 1; off < 64; off <<= 1) d += sx(d, off);
        z[j] = d + entry_b[j];
    }

    // ---- closed-form half-angle trig for RY(atan z), RZ(atan z^2) ----
    float cy[NQ], sy[NQ], cz[NQ], sz[NQ];
#pragma unroll
    for (int j = 0; j < NQ; ++j) {
        float zj = z[j];
        float c1 = rsqrtf(1.0f + zj * zj);               // cos(atan z)
        cy[j] = sqrtf(0.5f * (1.0f + c1));
        sy[j] = copysignf(sqrtf(fmaxf(0.5f * (1.0f - c1), 0.0f)), zj);
        float w  = zj * zj;
        float c2 = rsqrtf(1.0f + w * w);                 // cos(atan z^2)
        cz[j] = sqrtf(0.5f * (1.0f + c2));
        sz[j] = sqrtf(fmaxf(0.5f * (1.0f - c2), 0.0f));  // angle in [0,pi/2)
    }

    // ---- statevector: lane = basis index, amp = (ar, ai) ----
    float ar = (lane == 0) ? 1.0f : 0.0f;
    float ai = 0.0f;

    // encoding: H, RY, RZ per qubit
#pragma unroll
    for (int i = 0; i < NQ; ++i) {
        const int m = 1 << i;
        const bool b = (lane & m) != 0;
        // H
        float pr = sx(ar, m), pi = sx(ai, m);
        float s = b ? -1.0f : 1.0f;
        ar = 0.70710678118f * (pr + s * ar);
        ai = 0.70710678118f * (pi + s * ai);
        // RY
        pr = sx(ar, m); pi = sx(ai, m);
        float t = b ? sy[i] : -sy[i];
        ar = cy[i] * ar + t * pr;
        ai = cy[i] * ai + t * pi;
        // RZ (diagonal)
        float u = b ? -sz[i] : sz[i];
        float nr = cz[i] * ar + u * ai;
        ai = cz[i] * ai - u * ar;
        ar = nr;
    }

#pragma unroll
    for (int l = 0; l < 2; ++l) {
        // CNOT ring: ctrl i -> tgt (i+1)%6
#pragma unroll
        for (int i = 0; i < NQ; ++i) {
            const int cm = 1 << i;
            const int tm = 1 << ((i + 1) % NQ);
            float pr = sx(ar, tm), pi = sx(ai, tm);
            bool c = (lane & cm) != 0;
            ar = c ? pr : ar;
            ai = c ? pi : ai;
        }
        // parameterized RX, RY, RZ
#pragma unroll
        for (int i = 0; i < NQ; ++i) {
            const int m = 1 << i;
            const bool b = (lane & m) != 0;
            float2 wx = ((const float2*)wtrig)[l * 18 + 0 * 6 + i];
            float pr = sx(ar, m), pi = sx(ai, m);
            float nr = wx.x * ar + wx.y * pi;      // RX: c*self - i*s*partner
            ai = wx.x * ai - wx.y * pr;
            ar = nr;
            float2 wy = ((const float2*)wtrig)[l * 18 + 1 * 6 + i];
            pr = sx(ar, m); pi = sx(ai, m);
            float t = b ? wy.y : -wy.y;
            ar = wy.x * ar + t * pr;
            ai = wy.x * ai + t * pi;
            float2 wz = ((const float2*)wtrig)[l * 18 + 2 * 6 + i];
            float u = b ? -wz.y : wz.y;
            nr = wz.x * ar + u * ai;
            ai = wz.x * ai - u * ar;
            ar = nr;
        }
        // data re-upload after layer 0
        if (l == 0) {
#pragma unroll
            for (int i = 0; i < NQ; ++i) {
                const int m = 1 << i;
                const bool b = (lane & m) != 0;
                float pr = sx(ar, m), pi = sx(ai, m);
                float t = b ? sy[i] : -sy[i];
                ar = cy[i] * ar + t * pr;
                ai = cy[i] * ai + t * pi;
                float u = b ? -sz[i] : sz[i];
                float nr = cz[i] * ar + u * ai;
                ai = cz[i] * ai - u * ar;
                ar = nr;
            }
        }
    }

    // ---- measure <Z_i> and write zq tail ----
    float p = ar * ar + ai * ai;
    float qv[NQ];
#pragma unroll
    for (int i = 0; i < NQ; ++i) {
        float v = (lane & (1 << i)) ? -p : p;
#pragma unroll
        for (int off = 1; off < 64; off <<= 1) v += sx(v, off);
        qv[i] = v;
    }
    float tail = 0.0f;
#pragma unroll
    for (int j = 0; j < NQ; ++j) tail = (lane == j) ? (z[j] + qv[j]) : tail;
    if (lane < 32) xbf[(size_t)row * KP + 512 + lane] = f2bf(tail);
}

// ---------------------------------------------------------------------------
// kernel 2: C = A'[32768][544] @ W'[512][544]^T  (bf16 MFMA), + bias, LN, out
// block: 512 thr = 8 waves, tile 64 rows x 512 cols (full LN row in block)
// ---------------------------------------------------------------------------
__global__ __launch_bounds__(512) void k_gemm_ln(const u16* __restrict__ xbf,
                                                 const u16* __restrict__ Wbf,
                                                 const float* __restrict__ skip_b,
                                                 const float* __restrict__ exit_b,
                                                 const float* __restrict__ gamma,
                                                 const float* __restrict__ beta,
                                                 float* __restrict__ out) {
    __shared__ uint4 sAB[2304];          // A: slots 0..255 (64x32), B: 256..2303 (512x32)
    __shared__ float ps[8][64][2];
    __shared__ float stats[64][2];

    const int tid  = threadIdx.x;
    const int wid  = tid >> 6;
    const int lane = tid & 63;
    const int q    = lane >> 4;
    const int c16  = lane & 15;
    const int m0   = blockIdx.x * 64;

    f32x4 acc[4][4];
#pragma unroll
    for (int mt = 0; mt < 4; ++mt)
#pragma unroll
        for (int nt = 0; nt < 4; ++nt)
#pragma unroll
            for (int r = 0; r < 4; ++r) acc[mt][nt][r] = 0.0f;

    for (int ks = 0; ks < 17; ++ks) {
        // ---- stage A' (64x32) + W' (512x32) tiles, 16B chunks, XOR swizzle ----
        for (int c = tid; c < 2304; c += 512) {
            const u16* src;
            int slot;
            if (c < 256) {                       // A chunk
                int i = c >> 2, j4 = c & 3;
                slot = (i << 2) | (j4 ^ ((i >> 1) & 3));
                src = xbf + (size_t)(m0 + i) * KP + ks * 32 + j4 * 8;
            } else {                             // B chunk
                int cb = c - 256;
                int n = cb >> 2, j4 = cb & 3;
                slot = 256 + ((n << 2) | (j4 ^ ((n >> 1) & 3)));
                src = Wbf + (size_t)n * KP + ks * 32 + j4 * 8;
            }
            sAB[slot] = *(const uint4*)src;
        }
        __syncthreads();

        // ---- fragments + MFMA ----
        bf16x8 af[4], bf[4];
#pragma unroll
        for (int mt = 0; mt < 4; ++mt) {
            int row = mt * 16 + c16;
            int slot = (row << 2) | (q ^ ((row >> 1) & 3));
            af[mt] = *(const bf16x8*)&sAB[slot];
        }
#pragma unroll
        for (int nt = 0; nt < 4; ++nt) {
            int rowb = wid * 64 + nt * 16 + c16;
            int slot = 256 + ((rowb << 2) | (q ^ ((rowb >> 1) & 3)));
            bf[nt] = *(const bf16x8*)&sAB[slot];
        }
#pragma unroll
        for (int mt = 0; mt < 4; ++mt)
#pragma unroll
            for (int nt = 0; nt < 4; ++nt)
                acc[mt][nt] = __builtin_amdgcn_mfma_f32_16x16x32_bf16(af[mt], bf[nt], acc[mt][nt], 0, 0, 0);
        __syncthreads();
    }

    // ---- epilogue: bias, row sums, LN, store ----
    float bias[4], gg[4], bb[4];
#pragma unroll
    for (int nt = 0; nt < 4; ++nt) {
        int n = wid * 64 + nt * 16 + c16;
        bias[nt] = skip_b[n] + exit_b[n];
        gg[nt] = gamma[n];
        bb[nt] = beta[n];
    }
#pragma unroll
    for (int mt = 0; mt < 4; ++mt)
#pragma unroll
        for (int nt = 0; nt < 4; ++nt)
#pragma unroll
            for (int r = 0; r < 4; ++r) acc[mt][nt][r] += bias[nt];

#pragma unroll
    for (int mt = 0; mt < 4; ++mt)
#pragma unroll
        for (int r = 0; r < 4; ++r) {
            float s1 = 0.0f, s2 = 0.0f;
#pragma unroll
            for (int nt = 0; nt < 4; ++nt) {
                float v = acc[mt][nt][r];
                s1 += v; s2 += v * v;
            }
#pragma unroll
            for (int off = 1; off < 16; off <<= 1) {
                s1 += sx(s1, off);
                s2 += sx(s2, off);
            }
            if (c16 == r) {
                int m = mt * 16 + q * 4 + r;
                ps[wid][m][0] = s1;
                ps[wid][m][1] = s2;
            }
        }
    __syncthreads();
    if (tid < 64) {
        float s1 = 0.0f, s2 = 0.0f;
#pragma unroll
        for (int w2 = 0; w2 < 8; ++w2) { s1 += ps[w2][tid][0]; s2 += ps[w2][tid][1]; }
        float mu  = s1 * (1.0f / 512.0f);
        float var = s2 * (1.0f / 512.0f) - mu * mu;
        stats[tid][0] = mu;
        stats[tid][1] = rsqrtf(var + 1e-5f);
    }
    __syncthreads();

#pragma unroll
    for (int mt = 0; mt < 4; ++mt)
#pragma unroll
        for (int r = 0; r < 4; ++r) {
            int m = mt * 16 + q * 4 + r;
            float mu = stats[m][0], rs = stats[m][1];
#pragma unroll
            for (int nt = 0; nt < 4; ++nt) {
                float v = (acc[mt][nt][r] - mu) * rs * gg[nt] + bb[nt];
                out[(size_t)(m0 + m) * OUT_D + wid * 64 + nt * 16 + c16] = v;
            }
        }
}

// ---------------------------------------------------------------------------
extern "C" void kernel_launch(void* const* d_in, const int* in_sizes, int n_in,
                              void* d_out, int out_size, void* d_ws, size_t ws_size,
                              hipStream_t stream) {
    const float* x       = (const float*)d_in[0];
    const float* entry_w = (const float*)d_in[1];
    const float* entry_b = (const float*)d_in[2];
    const float* exit_w  = (const float*)d_in[3];
    const float* exit_b  = (const float*)d_in[4];
    const float* skip_w  = (const float*)d_in[5];
    const float* skip_b  = (const float*)d_in[6];
    const float* vqc_w   = (const float*)d_in[7];
    const float* gamma   = (const float*)d_in[8];
    const float* beta    = (const float*)d_in[9];
    float* out = (float*)d_out;

    char* ws = (char*)d_ws;
    u16*   xbf   = (u16*)(ws + WS_XBF);
    u16*   Wbf   = (u16*)(ws + WS_WBF);
    float* wtrig = (float*)(ws + WS_WTRIG);

    k_setup<<<dim3(512), dim3(64), 0, stream>>>(skip_w, exit_w, vqc_w, Wbf, wtrig);
    k_zq<<<dim3(MROWS / 4), dim3(256), 0, stream>>>(x, entry_w, entry_b, wtrig, xbf);
    k_gemm_ln<<<dim3(MROWS / 64), dim3(512), 0, stream>>>(xbf, Wbf, skip_b, exit_b, gamma, beta, out);
}